// Round 6
// baseline (908.033 us; speedup 1.0000x reference)
//
#include <hip/hip_runtime.h>
#include <hip/hip_bf16.h>
#include <stdint.h>

#define B_ 8
#define C_ 512
#define S_ 2048
#define L_ 8921
#define LTILE 128
#define NLT 70            // real L-tiles; grid pads to 72 for XCD slicing
#define NSC 16            // S / 128
#define ROUNDS 16         // C / 32

using f32x16 = __attribute__((ext_vector_type(16))) float;
using s16x8  = __attribute__((ext_vector_type(8))) short;   // 8 bf16 = 4 VGPRs

static __device__ __forceinline__ unsigned short f2bf(float f) {
    union { float f; uint32_t u; } a; a.f = f;
    uint32_t u = a.u;
    return (unsigned short)((u + 0x7fffu + ((u >> 16) & 1u)) >> 16);   // RTNE
}

// ---- fp32 -> bf16 elementwise (for W_attn / W_cls) ----
__global__ void cvt_w(const float* __restrict__ src, unsigned short* __restrict__ dst, int n4) {
    int i = blockIdx.x * 256 + threadIdx.x;
    if (i >= n4) return;
    float4 v = ((const float4*)src)[i];
    ushort4 o;
    o.x = f2bf(v.x); o.y = f2bf(v.y); o.z = f2bf(v.z); o.w = f2bf(v.w);
    ((ushort4*)dst)[i] = o;
}

// ---- encoded (B,C,S) fp32 -> Ebt (B,S,C) bf16, tiled transpose ----
__global__ void cvt_e(const float* __restrict__ enc, unsigned short* __restrict__ ebt) {
    __shared__ float tile[64][65];
    int x = blockIdx.x;
    int ct = (x & 7) * 64;          // C/64 = 8
    int st = ((x >> 3) & 31) * 64;  // S/64 = 32
    int b  = x >> 8;
    int t = threadIdx.x;
    const float* src = enc + (size_t)b * C_ * S_;
    #pragma unroll
    for (int it = 0; it < 16; ++it) {
        int idx = it * 256 + t;
        int rc = idx >> 6, rs = idx & 63;
        tile[rc][rs] = src[(size_t)(ct + rc) * S_ + st + rs];
    }
    __syncthreads();
    unsigned short* dst = ebt + (size_t)b * S_ * C_;
    #pragma unroll
    for (int it = 0; it < 16; ++it) {
        int idx = it * 256 + t;
        int rs = idx >> 6, rc = idx & 63;
        dst[(size_t)(st + rs) * C_ + ct + rc] = f2bf(tile[rc][rs]);
    }
}

// ---- fused scores/softmax/value main kernel ----
// Block: 128 L x 128 s, K=512 in 16 rounds of 32. Waves split by m only
// (wave = 32 L rows x all 128 s). NO LDS, NO BARRIERS: both the W A-frags
// and the E B-frags for 32x32x16 are 16 contiguous bytes of a k-major row,
// loaded global->VGPR directly (L1 serves the 4x E re-read across the
// block's waves; L2 unique traffic unchanged). Ping-pong double buffer,
// one full round of prefetch distance. Waves fully independent ->
// no vmcnt(0) drain, no phase-locking.
// Grid mapping pins lt%8 to (assumed) XCD x%8 so each XCD's W slice
// (~2.3 MB) stays L2-resident; 72 consecutive blocks share one E tile.
__global__ __launch_bounds__(256, 2) void attn_main(
    const unsigned short* __restrict__ ebt,
    const unsigned short* __restrict__ wa,
    const unsigned short* __restrict__ wc,
    float* __restrict__ pnum, float* __restrict__ pden)
{
    const int tid  = threadIdx.x;
    const int lane = tid & 63;
    const int wave = tid >> 6;

    // x = (bsc*9 + j)*8 + i ; lt = 8j + i (0..71, >=70 pad), bsc = b + 8*sc
    const int x   = blockIdx.x;
    const int i8  = x & 7;
    const int t9  = x >> 3;
    const int jj9 = t9 % 9;
    const int bsc = t9 / 9;
    const int lt  = jj9 * 8 + i8;
    const int b   = bsc & 7;
    const int sc  = bsc >> 3;
    const int l0  = lt * LTILE;
    const int s0  = sc * 128;

    const int h = lane >> 5;              // k-half within a 16-k step
    // ---- W row pointers (A-frag: row = lane&31, k = h*8 + [0,8)) ----
    int glRow = l0 + wave * 32 + (lane & 31);
    if (glRow > L_ - 1) glRow = L_ - 1;
    const unsigned short* waRow = wa + (size_t)glRow * C_ + h * 8;
    const unsigned short* wcRow = wc + (size_t)glRow * C_ + h * 8;
    // ---- E row pointers (B-frag: n-col = lane&31 -> s-row, k = h*8 + [0,8)) ----
    const unsigned short* eRow[4];
    #pragma unroll
    for (int nf = 0; nf < 4; ++nf)
        eRow[nf] = ebt + ((size_t)b * S_ + s0 + nf * 32 + (lane & 31)) * C_ + h * 8;

    // loads one round (32 k): W ksteps 0/1 for Wa,Wc + E ksteps 0/1 x 4 nf
    auto loadRound = [&](int rr, s16x8* wv, s16x8 (*ev)[2]) {
        const int co = rr * 32;
        wv[0] = *(const s16x8*)(waRow + co);
        wv[1] = *(const s16x8*)(waRow + co + 16);
        wv[2] = *(const s16x8*)(wcRow + co);
        wv[3] = *(const s16x8*)(wcRow + co + 16);
        #pragma unroll
        for (int nf = 0; nf < 4; ++nf) {
            ev[nf][0] = *(const s16x8*)(eRow[nf] + co);
            ev[nf][1] = *(const s16x8*)(eRow[nf] + co + 16);
        }
    };

    f32x16 accS[4], accV[4];
    #pragma unroll
    for (int nf = 0; nf < 4; ++nf)
        #pragma unroll
        for (int r = 0; r < 16; ++r) { accS[nf][r] = 0.f; accV[nf][r] = 0.f; }

    auto mfmaRound = [&](const s16x8* wv, const s16x8 (*ev)[2]) {
        #pragma unroll
        for (int nf = 0; nf < 4; ++nf) {
            accS[nf] = __builtin_amdgcn_mfma_f32_32x32x16_bf16(wv[0], ev[nf][0], accS[nf], 0, 0, 0);
            accV[nf] = __builtin_amdgcn_mfma_f32_32x32x16_bf16(wv[2], ev[nf][0], accV[nf], 0, 0, 0);
        }
        #pragma unroll
        for (int nf = 0; nf < 4; ++nf) {
            accS[nf] = __builtin_amdgcn_mfma_f32_32x32x16_bf16(wv[1], ev[nf][1], accS[nf], 0, 0, 0);
            accV[nf] = __builtin_amdgcn_mfma_f32_32x32x16_bf16(wv[3], ev[nf][1], accV[nf], 0, 0, 0);
        }
    };

    s16x8 wv0[4], wv1[4];
    s16x8 ev0[4][2], ev1[4][2];
    loadRound(0, wv0, ev0);
    #pragma unroll
    for (int rr2 = 0; rr2 < ROUNDS / 2; ++rr2) {
        loadRound(2 * rr2 + 1, wv1, ev1);
        mfmaRound(wv0, ev0);
        if (rr2 + 1 < ROUNDS / 2) loadRound(2 * rr2 + 2, wv0, ev0);
        mfmaRound(wv1, ev1);
    }

    // ---- epilogue: exp + s-reduction. C/D 32x32 layout: col = lane&31 (s),
    // row = (r&3) + 8*(r>>2) + 4*h. scores |.|<~3.5 -> exp safe without max.
    float numA[16], denA[16];
    #pragma unroll
    for (int r = 0; r < 16; ++r) { numA[r] = 0.f; denA[r] = 0.f; }
    #pragma unroll
    for (int nf = 0; nf < 4; ++nf)
        #pragma unroll
        for (int r = 0; r < 16; ++r) {
            float e = __expf(accS[nf][r]);
            denA[r] += e;
            numA[r] += e * accV[nf][r];
        }
    if (lt < NLT) {
        const size_t obase = ((size_t)((b * NLT + lt) * NSC + sc)) * LTILE;
        #pragma unroll
        for (int r = 0; r < 16; ++r) {
            float n = numA[r], d = denA[r];
            n += __shfl_xor(n, 1);   d += __shfl_xor(d, 1);
            n += __shfl_xor(n, 2);   d += __shfl_xor(d, 2);
            n += __shfl_xor(n, 4);   d += __shfl_xor(d, 4);
            n += __shfl_xor(n, 8);   d += __shfl_xor(d, 8);
            n += __shfl_xor(n, 16);  d += __shfl_xor(d, 16);
            if ((lane & 31) == 0) {
                int row = wave * 32 + (r & 3) + 8 * (r >> 2) + 4 * h;
                pnum[obase + row] = n;
                pden[obase + row] = d;
            }
        }
    }
}

// ---- combine s-chunk partials, divide, add b_cls ----
__global__ void finalize(const float* __restrict__ pnum, const float* __restrict__ pden,
                         const float* __restrict__ bcls, float* __restrict__ out) {
    int gid = blockIdx.x * 256 + threadIdx.x;
    if (gid >= B_ * L_) return;
    int b = gid / L_, l = gid - b * L_;
    int lt = l >> 7, row = l & 127;
    float n = 0.f, d = 0.f;
    #pragma unroll
    for (int s = 0; s < NSC; ++s) {
        size_t idx = ((size_t)((b * NLT + lt) * NSC + s)) * LTILE + row;
        n += pnum[idx];
        d += pden[idx];
    }
    out[gid] = n / d + bcls[l];
}

extern "C" void kernel_launch(void* const* d_in, const int* in_sizes, int n_in,
                              void* d_out, int out_size, void* d_ws, size_t ws_size,
                              hipStream_t stream) {
    (void)in_sizes; (void)n_in; (void)out_size; (void)ws_size;
    const float* enc  = (const float*)d_in[0];
    const float* Wa   = (const float*)d_in[1];
    // d_in[2] = b_attn: cancels in softmax over S — unused.
    const float* Wc   = (const float*)d_in[3];
    const float* bcls = (const float*)d_in[4];

    unsigned char* ws = (unsigned char*)d_ws;
    const size_t oEbt = 0;                          // B*S*C*2  = 16,777,216
    const size_t oWa  = oEbt + 16777216;            // L*C*2    =  9,135,104 (+pad)
    const size_t oWc  = oWa + 9136128;
    const size_t oPn  = oWc + 9136128;              // 8*70*16*128*4 = 4,587,520
    const size_t oPd  = oPn + 4587520;              // total ~42.2 MiB

    unsigned short* ebt  = (unsigned short*)(ws + oEbt);
    unsigned short* waBf = (unsigned short*)(ws + oWa);
    unsigned short* wcBf = (unsigned short*)(ws + oWc);
    float* pnum = (float*)(ws + oPn);
    float* pden = (float*)(ws + oPd);

    const int n4 = (L_ * C_) / 4;
    cvt_w<<<(n4 + 255) / 256, 256, 0, stream>>>(Wa, waBf, n4);
    cvt_w<<<(n4 + 255) / 256, 256, 0, stream>>>(Wc, wcBf, n4);
    cvt_e<<<B_ * 32 * 8, 256, 0, stream>>>(enc, ebt);
    attn_main<<<128 * 9 * 8, 256, 0, stream>>>(ebt, waBf, wcBf, pnum, pden);
    finalize<<<(B_ * L_ + 255) / 256, 256, 0, stream>>>(pnum, pden, bcls, (float*)d_out);
}

// Round 7
// 441.227 us; speedup vs baseline: 2.0580x; 2.0580x over previous
//
#include <hip/hip_runtime.h>
#include <hip/hip_bf16.h>
#include <stdint.h>

#define B_ 8
#define C_ 512
#define S_ 2048
#define L_ 8921
#define LTILE 128
#define NLT 70            // real L-tiles; grid pads to 72 for XCD slicing
#define NLTP 72
#define NSC 16            // S / 128
#define ROUNDS 16         // C / 32

using f32x16 = __attribute__((ext_vector_type(16))) float;
using s16x8  = __attribute__((ext_vector_type(8))) short;   // 8 bf16 = 4 VGPRs

static __device__ __forceinline__ unsigned short f2bf(float f) {
    union { float f; uint32_t u; } a; a.f = f;
    uint32_t u = a.u;
    return (unsigned short)((u + 0x7fffu + ((u >> 16) & 1u)) >> 16);   // RTNE
}

// ---- fp32 W (L x C) -> bf16 A-fragment-major layout ----
// frag index f = ((lt*4 + wv)*16 + rr)*2 + kstep ; frag = 64 lanes x 16 B.
// lane holds rows lt*128+wv*32+(lane&31), k = rr*32+kstep*16+(lane>>5)*8+[0,8).
// Main kernel then loads W as base + lane*16 — fully coalesced, no gathers.
__global__ void cvt_wfrag(const float* __restrict__ src, unsigned short* __restrict__ dst) {
    int gid = blockIdx.x * 256 + threadIdx.x;          // over 72*4*16*2*64
    int lane = gid & 63;
    int f    = gid >> 6;
    int kstep = f & 1;
    int rr    = (f >> 1) & 15;
    int wv    = (f >> 5) & 3;
    int lt    = f >> 7;
    int row = lt * 128 + wv * 32 + (lane & 31);
    if (row > L_ - 1) row = L_ - 1;
    int k0 = rr * 32 + kstep * 16 + (lane >> 5) * 8;
    const float* s = src + (size_t)row * C_ + k0;
    float4 v0 = ((const float4*)s)[0];
    float4 v1 = ((const float4*)s)[1];
    ushort4 o0, o1;
    o0.x = f2bf(v0.x); o0.y = f2bf(v0.y); o0.z = f2bf(v0.z); o0.w = f2bf(v0.w);
    o1.x = f2bf(v1.x); o1.y = f2bf(v1.y); o1.z = f2bf(v1.z); o1.w = f2bf(v1.w);
    ushort4* d = (ushort4*)(dst + (size_t)gid * 8);
    d[0] = o0; d[1] = o1;
}

// ---- encoded (B,C,S) fp32 -> Ebt (B,S,C) bf16, tiled transpose ----
__global__ void cvt_e(const float* __restrict__ enc, unsigned short* __restrict__ ebt) {
    __shared__ float tile[64][65];
    int x = blockIdx.x;
    int ct = (x & 7) * 64;          // C/64 = 8
    int st = ((x >> 3) & 31) * 64;  // S/64 = 32
    int b  = x >> 8;
    int t = threadIdx.x;
    const float* src = enc + (size_t)b * C_ * S_;
    #pragma unroll
    for (int it = 0; it < 16; ++it) {
        int idx = it * 256 + t;
        int rc = idx >> 6, rs = idx & 63;
        tile[rc][rs] = src[(size_t)(ct + rc) * S_ + st + rs];
    }
    __syncthreads();
    unsigned short* dst = ebt + (size_t)b * S_ * C_;
    #pragma unroll
    for (int it = 0; it < 16; ++it) {
        int idx = it * 256 + t;
        int rs = idx >> 6, rc = idx & 63;
        dst[(size_t)(st + rs) * C_ + ct + rc] = f2bf(tile[rc][rs]);
    }
}

// ---- fused scores/softmax/value main kernel ----
// Block: 128 L x 128 s, K=512 in 16 rounds of 32. Waves split by m only
// (wave = 32 L rows x all 128 s; E frags shared by both GEMMs).
// W: COALESCED global->VGPR from fragment-major precomputed layout
// (base + lane*16), prefetched one round ahead — no row gathers (R6 showed
// gathers cost ~2 cyc/line; R3/R5's W gathers were ~60% of round time).
// E: glds double-buffer 2x8KB, one barrier per round; b128 frag reads with
// chunk swizzle ck ^ ((r>>1)&3) (4-sweep inherent, no extra conflicts).
// Grid pins lt%8 to XCD x%8: W slice L2-resident per XCD.
__global__ __launch_bounds__(256, 2) void attn_main(
    const unsigned short* __restrict__ ebt,
    const unsigned short* __restrict__ wfa,
    const unsigned short* __restrict__ wfc,
    float* __restrict__ pnum, float* __restrict__ pden)
{
    __shared__ __align__(16) unsigned char sE[16384];   // 2 x 8 KB E k-slabs

    const int tid  = threadIdx.x;
    const int lane = tid & 63;
    const int wave = tid >> 6;

    // x = (bsc*9 + j)*8 + i ; lt = 8j + i (0..71, >=70 pad), bsc = b + 8*sc
    const int x   = blockIdx.x;
    const int i8  = x & 7;
    const int t9  = x >> 3;
    const int jj9 = t9 % 9;
    const int bsc = t9 / 9;
    const int lt  = jj9 * 8 + i8;
    const int b   = bsc & 7;
    const int sc  = bsc >> 3;
    const int s0  = sc * 128;

    const int h = lane >> 5;              // k-half within a 16-k step
    // ---- W fragment-major pointers: 32 frags (16 rr x 2 kstep) per (lt,wave) ----
    const unsigned short* waF = wfa + ((size_t)(lt * 4 + wave) * 32) * 512 + lane * 8;
    const unsigned short* wcF = wfc + ((size_t)(lt * 4 + wave) * 32) * 512 + lane * 8;

    // ---- E staging constants (per glds: 16 s-rows x 4 chunks, lane-contig dst) ----
    const int slRow  = lane >> 2;
    const int srcCk  = (((lane & 3) ^ ((slRow >> 1) & 3)) << 3);   // elems
    const unsigned short* eg0 = ebt + ((size_t)b * S_ + s0 + (wave * 2) * 16 + slRow) * C_ + srcCk;
    const unsigned short* eg1 = eg0 + (size_t)16 * C_;
    const int ldst0 = (wave * 2) * 1024 + slRow * 64 + (lane & 3) * 16;
    const int ldst1 = ldst0 + 1024;

    auto stage = [&](int rr) {
        const int c0 = rr * 32;
        const int bufo = (rr & 1) << 13;
        __builtin_amdgcn_global_load_lds(
            (__attribute__((address_space(1))) void*)(eg0 + c0),
            (__attribute__((address_space(3))) void*)(sE + bufo + ldst0), 16, 0, 0);
        __builtin_amdgcn_global_load_lds(
            (__attribute__((address_space(1))) void*)(eg1 + c0),
            (__attribute__((address_space(3))) void*)(sE + bufo + ldst1), 16, 0, 0);
    };

    struct WREG { s16x8 a0, a1, c0, c1; };      // ksteps 0/1 of Wa, Wc
    auto loadW = [&](int rr) -> WREG {
        WREG w;
        w.a0 = *(const s16x8*)(waF + (size_t)(rr * 2 + 0) * 512);
        w.a1 = *(const s16x8*)(waF + (size_t)(rr * 2 + 1) * 512);
        w.c0 = *(const s16x8*)(wcF + (size_t)(rr * 2 + 0) * 512);
        w.c1 = *(const s16x8*)(wcF + (size_t)(rr * 2 + 1) * 512);
        return w;
    };

    // ---- E frag-read constants: row = nf*32 + (lane&31), phys chunk = (2j+h)^((lane>>1)&3)
    const int rowB  = (lane & 31) * 64;
    const int swz   = (lane >> 1) & 3;

    f32x16 accS[4], accV[4];
    #pragma unroll
    for (int nf = 0; nf < 4; ++nf)
        #pragma unroll
        for (int r = 0; r < 16; ++r) { accS[nf][r] = 0.f; accV[nf][r] = 0.f; }

    stage(0);
    WREG wcur = loadW(0);

    for (int rr = 0; rr < ROUNDS; ++rr) {
        __syncthreads();                        // stage(rr) + W loads drained
        if (rr + 1 < ROUNDS) stage(rr + 1);
        WREG wnxt = (rr + 1 < ROUNDS) ? loadW(rr + 1) : wcur;

        const unsigned char* db = sE + ((rr & 1) << 13);
        // kstep 0
        {
            s16x8 fe[4];
            #pragma unroll
            for (int nf = 0; nf < 4; ++nf) {
                const int off = (nf << 11) + rowB + (((0 + h) ^ swz) << 4);
                fe[nf] = *(const s16x8*)(db + off);
            }
            #pragma unroll
            for (int nf = 0; nf < 4; ++nf) {
                accS[nf] = __builtin_amdgcn_mfma_f32_32x32x16_bf16(wcur.a0, fe[nf], accS[nf], 0, 0, 0);
                accV[nf] = __builtin_amdgcn_mfma_f32_32x32x16_bf16(wcur.c0, fe[nf], accV[nf], 0, 0, 0);
            }
        }
        // kstep 1
        {
            s16x8 fe[4];
            #pragma unroll
            for (int nf = 0; nf < 4; ++nf) {
                const int off = (nf << 11) + rowB + (((2 + h) ^ swz) << 4);
                fe[nf] = *(const s16x8*)(db + off);
            }
            #pragma unroll
            for (int nf = 0; nf < 4; ++nf) {
                accS[nf] = __builtin_amdgcn_mfma_f32_32x32x16_bf16(wcur.a1, fe[nf], accS[nf], 0, 0, 0);
                accV[nf] = __builtin_amdgcn_mfma_f32_32x32x16_bf16(wcur.c1, fe[nf], accV[nf], 0, 0, 0);
            }
        }
        wcur = wnxt;
    }

    // ---- epilogue: exp + s-reduction. C/D 32x32 layout: col = lane&31 (s),
    // row = (r&3) + 8*(r>>2) + 4*h. scores |.|<~3.5 -> exp safe without max.
    float numA[16], denA[16];
    #pragma unroll
    for (int r = 0; r < 16; ++r) { numA[r] = 0.f; denA[r] = 0.f; }
    #pragma unroll
    for (int nf = 0; nf < 4; ++nf)
        #pragma unroll
        for (int r = 0; r < 16; ++r) {
            float e = __expf(accS[nf][r]);
            denA[r] += e;
            numA[r] += e * accV[nf][r];
        }
    if (lt < NLT) {
        const size_t obase = ((size_t)((b * NLT + lt) * NSC + sc)) * LTILE;
        #pragma unroll
        for (int r = 0; r < 16; ++r) {
            float n = numA[r], d = denA[r];
            n += __shfl_xor(n, 1);   d += __shfl_xor(d, 1);
            n += __shfl_xor(n, 2);   d += __shfl_xor(d, 2);
            n += __shfl_xor(n, 4);   d += __shfl_xor(d, 4);
            n += __shfl_xor(n, 8);   d += __shfl_xor(d, 8);
            n += __shfl_xor(n, 16);  d += __shfl_xor(d, 16);
            if ((lane & 31) == 0) {
                int row = wave * 32 + (r & 3) + 8 * (r >> 2) + 4 * h;
                pnum[obase + row] = n;
                pden[obase + row] = d;
            }
        }
    }
}

// ---- combine s-chunk partials, divide, add b_cls ----
__global__ void finalize(const float* __restrict__ pnum, const float* __restrict__ pden,
                         const float* __restrict__ bcls, float* __restrict__ out) {
    int gid = blockIdx.x * 256 + threadIdx.x;
    if (gid >= B_ * L_) return;
    int b = gid / L_, l = gid - b * L_;
    int lt = l >> 7, row = l & 127;
    float n = 0.f, d = 0.f;
    #pragma unroll
    for (int s = 0; s < NSC; ++s) {
        size_t idx = ((size_t)((b * NLT + lt) * NSC + s)) * LTILE + row;
        n += pnum[idx];
        d += pden[idx];
    }
    out[gid] = n / d + bcls[l];
}

extern "C" void kernel_launch(void* const* d_in, const int* in_sizes, int n_in,
                              void* d_out, int out_size, void* d_ws, size_t ws_size,
                              hipStream_t stream) {
    (void)in_sizes; (void)n_in; (void)out_size; (void)ws_size;
    const float* enc  = (const float*)d_in[0];
    const float* Wa   = (const float*)d_in[1];
    // d_in[2] = b_attn: cancels in softmax over S — unused.
    const float* Wc   = (const float*)d_in[3];
    const float* bcls = (const float*)d_in[4];

    unsigned char* ws = (unsigned char*)d_ws;
    const size_t oEbt = 0;                          // B*S*C*2  = 16,777,216
    const size_t oWa  = oEbt + 16777216;            // 72*128KB =  9,437,184
    const size_t oWc  = oWa + 9437184;
    const size_t oPn  = oWc + 9437184;              // 8*70*16*128*4 = 4,587,520
    const size_t oPd  = oPn + 4587520;              // total ~44.8 MB

    unsigned short* ebt = (unsigned short*)(ws + oEbt);
    unsigned short* wfa = (unsigned short*)(ws + oWa);
    unsigned short* wfc = (unsigned short*)(ws + oWc);
    float* pnum = (float*)(ws + oPn);
    float* pden = (float*)(ws + oPd);

    const int wThreads = NLTP * 4 * ROUNDS * 2 * 64;    // 589,824
    cvt_wfrag<<<wThreads / 256, 256, 0, stream>>>(Wa, wfa);
    cvt_wfrag<<<wThreads / 256, 256, 0, stream>>>(Wc, wfc);
    cvt_e<<<B_ * 32 * 8, 256, 0, stream>>>(enc, ebt);
    attn_main<<<128 * 9 * 8, 256, 0, stream>>>(ebt, wfa, wfc, pnum, pden);
    finalize<<<(B_ * L_ + 255) / 256, 256, 0, stream>>>(pnum, pden, bcls, (float*)d_out);
}